// Round 5
// baseline (10155.287 us; speedup 1.0000x reference)
//
#include <hip/hip_runtime.h>
#include <hip/hip_bf16.h>
#include <hip/hip_cooperative_groups.h>

namespace cg = cooperative_groups;

#define SEQ 512
#define BATCH 128
#define INP 512
#define HID 1024
#define CLASSES 1000
#define KTOT (INP + HID)      // 1536
#define NKT (KTOT / 32)       // 48 k-tiles
#define NKX (INP / 32)        // 16 x k-tiles
#define NKH (HID / 32)        // 32 h k-tiles

#define NBLK 128
#define NTHR 256              // 4 waves, M=32 per wave
#define BJ 8                  // h-columns per block
#define BN 32                 // gate-rows per block (4 gates x BJ)
#define NFLAG (NBLK * 4)      // per-wave flags: 512

typedef float f32x4 __attribute__((ext_vector_type(4)));
typedef short bf16x8 __attribute__((ext_vector_type(8)));

__device__ __forceinline__ short f2bf16s(float f) {
    __hip_bfloat16 h = __float2bfloat16(f);
    return __builtin_bit_cast(short, h);
}
__device__ __forceinline__ float sigmoidf_(float x) {
    return 1.0f / (1.0f + __expf(-x));
}
__device__ __forceinline__ float tanhf_(float x) {
    x = fminf(fmaxf(x, -15.0f), 15.0f);
    float e = __expf(2.0f * x);
    return (e - 1.0f) / (e + 1.0f);
}

// ---- fence-free coherence ----
// All cross-block data (h, flags) moves via relaxed AGENT-scope atomics,
// which bypass L1/L2 and hit the device-coherent point (L3) directly.
// NO acquire/release fences anywhere in the loop -> L2 stays warm for
// x/W_fc, and no per-step buffer_inv on the critical path.
// Visibility of this mechanism is already proven: rounds 2-4 polled flags
// with exactly these loads, fence-free, and passed deterministically.

__device__ __forceinline__ void wave_signal(unsigned* flags, int idx, unsigned val) {
    __hip_atomic_store(&flags[idx], val, __ATOMIC_RELAXED,
                       __HIP_MEMORY_SCOPE_AGENT);
}
// every wave polls all 512 per-wave flags: 8 words/lane, one L3 RTT per iter
__device__ __forceinline__ void wave_wait_all(const unsigned* flags, int lane,
                                              unsigned want) {
    for (;;) {
        unsigned ok = 1u;
        #pragma unroll
        for (int i = 0; i < 8; i++) {
            unsigned f = __hip_atomic_load(&flags[lane + 64 * i], __ATOMIC_RELAXED,
                                           __HIP_MEMORY_SCOPE_AGENT);
            ok &= (unsigned)(f >= want);
        }
        if (__all(ok)) break;
        __builtin_amdgcn_s_sleep(1);
    }
}

__device__ __forceinline__ bf16x8 load_h16(const unsigned long long* p) {
    union { unsigned long long q[2]; bf16x8 v; } u;
    u.q[0] = __hip_atomic_load(p,     __ATOMIC_RELAXED, __HIP_MEMORY_SCOPE_AGENT);
    u.q[1] = __hip_atomic_load(p + 1, __ATOMIC_RELAXED, __HIP_MEMORY_SCOPE_AGENT);
    return u.v;
}

__global__ __launch_bounds__(NTHR)
void lstm_fused(const float* __restrict__ x,
                const float* __restrict__ W_ih,
                const float* __restrict__ W_hh,
                const float* __restrict__ b_ih,
                const float* __restrict__ b_hh,
                const float* __restrict__ W_fc,
                const float* __restrict__ b_fc,
                float* __restrict__ out,
                unsigned short* __restrict__ h0,
                unsigned short* __restrict__ h1,
                unsigned short* __restrict__ xbf,
                int use_xbf,
                unsigned* __restrict__ flags)
{
    // W in MFMA-fragment order: [nt][kt][lane][8] -> conflict-free ds_read_b128
    __shared__ short W_sw[2 * NKT * 64 * 8];   // 98304 B
    __shared__ float gw[4][32][33];            // per-wave gate transpose, 16896 B

    const int tid = threadIdx.x;
    const int bid = blockIdx.x;
    const int j0 = bid * BJ;

    // ---------------- one-time init ----------------
    for (int f = tid; f < 2 * NKT * 64; f += NTHR) {    // 24 iters
        const int ln = f & 63;
        const int kt = (f >> 6) % NKT;
        const int nt = f / (NKT * 64);
        const int n = nt * 16 + (ln & 15);              // block n-index 0..31
        const int r = (n >> 3) * HID + j0 + (n & 7);    // global gate row
        const int kbase = kt * 32 + (ln >> 4) * 8;
        short tmp[8];
        #pragma unroll
        for (int j = 0; j < 8; j++) {
            const int k = kbase + j;
            float w = (k < INP) ? W_ih[(size_t)r * INP + k]
                                : W_hh[(size_t)r * HID + (k - INP)];
            tmp[j] = f2bf16s(w);
        }
        *(bf16x8*)&W_sw[(size_t)f * 8] = *(bf16x8*)tmp;
    }
    {   // zero h0: 65536 dwords over 32768 grid threads
        const unsigned g = (unsigned)bid * NTHR + tid;
        ((unsigned*)h0)[g] = 0u;
        ((unsigned*)h0)[g + (unsigned)NBLK * NTHR] = 0u;
    }
    if (bid == 0) {
        for (int i = tid; i < NFLAG; i += NTHR) flags[i] = 0u;
    }
    if (use_xbf) {                                      // x fp32 -> bf16 once
        const size_t total8 = (size_t)SEQ * BATCH * INP / 8;
        for (size_t c = (size_t)bid * NTHR + tid; c < total8;
             c += (size_t)NBLK * NTHR) {
            const float* src = x + c * 8;
            const float4 a = *(const float4*)src;
            const float4 b = *(const float4*)(src + 4);
            bf16x8 v;
            v[0] = f2bf16s(a.x); v[1] = f2bf16s(a.y);
            v[2] = f2bf16s(a.z); v[3] = f2bf16s(a.w);
            v[4] = f2bf16s(b.x); v[5] = f2bf16s(b.y);
            v[6] = f2bf16s(b.z); v[7] = f2bf16s(b.w);
            *(bf16x8*)(xbf + c * 8) = v;
        }
    }

    const int wave = tid >> 6;          // 0..3 -> M-block of 32 batch rows
    const int lane = tid & 63;
    const int ln15 = lane & 15;
    const int lgrp = lane >> 4;         // 0..3
    const int arow0 = wave * 32 + ln15; // first M-tile batch row
    const int k8 = lgrp * 8;

    // per-thread recurrent state in registers
    const int bl  = lane >> 1;               // local batch row 0..31
    const int bg  = wave * 32 + bl;          // global batch row
    const int djb = (lane & 1) * 4;          // first of 4 h-columns
    float c_r[4] = {0.f, 0.f, 0.f, 0.f};
    float bias_r[16];                        // [gate][j]
    #pragma unroll
    for (int g = 0; g < 4; g++)
        #pragma unroll
        for (int j = 0; j < 4; j++) {
            const int r = g * HID + j0 + djb + j;
            bias_r[g * 4 + j] = b_ih[r] + b_hh[r];
        }

    __syncthreads();
    cg::this_grid().sync();   // publish h0/xbf/flags to all blocks

    const bf16x8* Wl = (const bf16x8*)W_sw + lane;     // + (nt*NKT + kt)*64
    const int wfl = bid * 4 + wave;                    // own flag index

    for (int t = 0; t < SEQ; t++) {
        const unsigned short* __restrict__ hp = (t & 1) ? h1 : h0;
        unsigned short* __restrict__ hc       = (t & 1) ? h0 : h1;

        f32x4 acc00 = {0.f,0.f,0.f,0.f}, acc01 = {0.f,0.f,0.f,0.f};
        f32x4 acc10 = {0.f,0.f,0.f,0.f}, acc11 = {0.f,0.f,0.f,0.f};

        // ---- x-part (independent of h_t): runs while others finish t-1 ----
        if (use_xbf) {
            const unsigned short* xr0 =
                xbf + (size_t)t * (BATCH * INP) + (size_t)arow0 * INP + k8;
            const unsigned short* xr1 = xr0 + 16 * INP;
            #pragma unroll
            for (int kt = 0; kt < NKX; kt++) {
                bf16x8 a0 = *(const bf16x8*)(xr0 + kt * 32);
                bf16x8 a1 = *(const bf16x8*)(xr1 + kt * 32);
                bf16x8 b0 = Wl[kt * 64];
                bf16x8 b1 = Wl[(NKT + kt) * 64];
                acc00 = __builtin_amdgcn_mfma_f32_16x16x32_bf16(a0, b0, acc00, 0, 0, 0);
                acc01 = __builtin_amdgcn_mfma_f32_16x16x32_bf16(a0, b1, acc01, 0, 0, 0);
                acc10 = __builtin_amdgcn_mfma_f32_16x16x32_bf16(a1, b0, acc10, 0, 0, 0);
                acc11 = __builtin_amdgcn_mfma_f32_16x16x32_bf16(a1, b1, acc11, 0, 0, 0);
            }
        } else {
            const float* xr0 =
                x + (size_t)t * (BATCH * INP) + (size_t)arow0 * INP + k8;
            const float* xr1 = xr0 + 16 * INP;
            #pragma unroll
            for (int kt = 0; kt < NKX; kt++) {
                const float4 xa = *(const float4*)(xr0 + kt * 32);
                const float4 xb = *(const float4*)(xr0 + kt * 32 + 4);
                const float4 ya = *(const float4*)(xr1 + kt * 32);
                const float4 yb = *(const float4*)(xr1 + kt * 32 + 4);
                bf16x8 a0, a1;
                a0[0]=f2bf16s(xa.x); a0[1]=f2bf16s(xa.y); a0[2]=f2bf16s(xa.z); a0[3]=f2bf16s(xa.w);
                a0[4]=f2bf16s(xb.x); a0[5]=f2bf16s(xb.y); a0[6]=f2bf16s(xb.z); a0[7]=f2bf16s(xb.w);
                a1[0]=f2bf16s(ya.x); a1[1]=f2bf16s(ya.y); a1[2]=f2bf16s(ya.z); a1[3]=f2bf16s(ya.w);
                a1[4]=f2bf16s(yb.x); a1[5]=f2bf16s(yb.y); a1[6]=f2bf16s(yb.z); a1[7]=f2bf16s(yb.w);
                bf16x8 b0 = Wl[kt * 64];
                bf16x8 b1 = Wl[(NKT + kt) * 64];
                acc00 = __builtin_amdgcn_mfma_f32_16x16x32_bf16(a0, b0, acc00, 0, 0, 0);
                acc01 = __builtin_amdgcn_mfma_f32_16x16x32_bf16(a0, b1, acc01, 0, 0, 0);
                acc10 = __builtin_amdgcn_mfma_f32_16x16x32_bf16(a1, b0, acc10, 0, 0, 0);
                acc11 = __builtin_amdgcn_mfma_f32_16x16x32_bf16(a1, b1, acc11, 0, 0, 0);
            }
        }

        // ---- wait until every wave of every block published h_t ----
        wave_wait_all(flags, lane, (unsigned)t);

        // ---- h-part: agent-scope atomic loads (coherent, no fence) ----
        {
            const unsigned long long* hq0 =
                (const unsigned long long*)(hp + (size_t)arow0 * HID) + lgrp * 2;
            const unsigned long long* hq1 = hq0 + 16 * (HID / 4);
            #pragma unroll
            for (int kt = 0; kt < NKH; kt++) {
                bf16x8 a0 = load_h16(hq0 + kt * 8);
                bf16x8 a1 = load_h16(hq1 + kt * 8);
                bf16x8 b0 = Wl[(NKX + kt) * 64];
                bf16x8 b1 = Wl[(NKT + NKX + kt) * 64];
                acc00 = __builtin_amdgcn_mfma_f32_16x16x32_bf16(a0, b0, acc00, 0, 0, 0);
                acc01 = __builtin_amdgcn_mfma_f32_16x16x32_bf16(a0, b1, acc01, 0, 0, 0);
                acc10 = __builtin_amdgcn_mfma_f32_16x16x32_bf16(a1, b0, acc10, 0, 0, 0);
                acc11 = __builtin_amdgcn_mfma_f32_16x16x32_bf16(a1, b1, acc11, 0, 0, 0);
            }
        }

        // ---- transpose via WAVE-PRIVATE LDS (no block barrier needed) ----
        {
            const int r0 = lgrp * 4;
            #pragma unroll
            for (int r = 0; r < 4; r++) {
                gw[wave][r0 + r][ln15]           = acc00[r];
                gw[wave][r0 + r][16 + ln15]      = acc01[r];
                gw[wave][16 + r0 + r][ln15]      = acc10[r];
                gw[wave][16 + r0 + r][16 + ln15] = acc11[r];
            }
        }
        // compiler inserts lgkmcnt between these same-wave LDS ops

        // ---- cell update: 4 cells/thread, own wave's rows only ----
        {
            unsigned long long pack = 0;
            #pragma unroll
            for (int j = 0; j < 4; j++) {
                const int dj = djb + j;
                float ig = gw[wave][bl][dj]      + bias_r[j];
                float fg = gw[wave][bl][8 + dj]  + bias_r[4 + j];
                float gg = gw[wave][bl][16 + dj] + bias_r[8 + j];
                float og = gw[wave][bl][24 + dj] + bias_r[12 + j];
                ig = sigmoidf_(ig); fg = sigmoidf_(fg);
                gg = tanhf_(gg);    og = sigmoidf_(og);
                float c = fg * c_r[j] + ig * gg;
                c_r[j] = c;
                float h = og * tanhf_(c);
                pack |= ((unsigned long long)(unsigned short)f2bf16s(h)) << (16 * j);
            }
            __hip_atomic_store((unsigned long long*)(hc + (size_t)bg * HID + j0 + djb),
                               pack, __ATOMIC_RELAXED, __HIP_MEMORY_SCOPE_AGENT);
        }
        asm volatile("s_waitcnt vmcnt(0)" ::: "memory");  // wave's h acked at L3
        if (lane == 0) wave_signal(flags, wfl, (unsigned)(t + 1));
    }

    // all blocks done; h_last is in h0 (SEQ even). Full fence via cg sync.
    cg::this_grid().sync();

    // ---- FC epilogue: 128000 outputs over 32768 threads (4 iters) ----
    for (unsigned idx = (unsigned)bid * NTHR + tid; idx < BATCH * CLASSES;
         idx += (unsigned)NBLK * NTHR) {
        const int b   = idx / CLASSES;
        const int cls = idx % CLASSES;
        const unsigned short* hrow = h0 + (size_t)b * HID;
        const float* wrow = W_fc + (size_t)cls * HID;
        float acc = 0.f;
        #pragma unroll 4
        for (int k = 0; k < HID; k += 8) {
            bf16x8 hv = *(const bf16x8*)(hrow + k);
            float4 w0 = *(const float4*)(wrow + k);
            float4 w1 = *(const float4*)(wrow + k + 4);
            union { unsigned u; float f; } e;
            float s = 0.f;
            e.u = ((unsigned)(unsigned short)hv[0]) << 16; s += e.f * w0.x;
            e.u = ((unsigned)(unsigned short)hv[1]) << 16; s += e.f * w0.y;
            e.u = ((unsigned)(unsigned short)hv[2]) << 16; s += e.f * w0.z;
            e.u = ((unsigned)(unsigned short)hv[3]) << 16; s += e.f * w0.w;
            e.u = ((unsigned)(unsigned short)hv[4]) << 16; s += e.f * w1.x;
            e.u = ((unsigned)(unsigned short)hv[5]) << 16; s += e.f * w1.y;
            e.u = ((unsigned)(unsigned short)hv[6]) << 16; s += e.f * w1.z;
            e.u = ((unsigned)(unsigned short)hv[7]) << 16; s += e.f * w1.w;
            acc += s;
        }
        out[idx] = acc + b_fc[cls];
    }
}

extern "C" void kernel_launch(void* const* d_in, const int* in_sizes, int n_in,
                              void* d_out, int out_size, void* d_ws, size_t ws_size,
                              hipStream_t stream) {
    const float* x    = (const float*)d_in[0];
    const float* W_ih = (const float*)d_in[1];
    const float* W_hh = (const float*)d_in[2];
    const float* b_ih = (const float*)d_in[3];
    const float* b_hh = (const float*)d_in[4];
    const float* W_fc = (const float*)d_in[5];
    const float* b_fc = (const float*)d_in[6];
    float* out = (float*)d_out;

    unsigned short* h0 = (unsigned short*)d_ws;                      // 256 KB
    unsigned short* h1 = h0 + (size_t)BATCH * HID;                   // 256 KB
    unsigned short* xbf = (unsigned short*)((char*)d_ws + 524288);   // 64 MB opt
    const size_t need_xbf = 524288 + (size_t)SEQ * BATCH * INP * 2;
    int use_xbf = (ws_size >= need_xbf) ? 1 : 0;
    unsigned* flags = (unsigned*)d_out;  // 512 words; overwritten by FC at end

    void* args[] = {&x, &W_ih, &W_hh, &b_ih, &b_hh, &W_fc, &b_fc,
                    &out, &h0, &h1, &xbf, &use_xbf, &flags};
    hipLaunchCooperativeKernel((void*)lstm_fused, dim3(NBLK), dim3(NTHR),
                               args, 0, stream);
}

// Round 6
// 6771.792 us; speedup vs baseline: 1.4996x; 1.4996x over previous
//
#include <hip/hip_runtime.h>
#include <hip/hip_bf16.h>
#include <hip/hip_cooperative_groups.h>

namespace cg = cooperative_groups;

#define SEQ 512
#define BATCH 128
#define INP 512
#define HID 1024
#define CLASSES 1000
#define KTOT (INP + HID)      // 1536
#define NKT (KTOT / 32)       // 48 k-tiles
#define NKX (INP / 32)        // 16 x k-tiles
#define NKH (HID / 32)        // 32 h k-tiles

#define NBLK 128
#define NTHR 512              // 8 waves, M=16 per wave
#define BJ 8                  // h-columns per block
#define BN 32                 // gate-rows per block (4 gates x BJ)

typedef float f32x4 __attribute__((ext_vector_type(4)));
typedef short bf16x8 __attribute__((ext_vector_type(8)));

__device__ __forceinline__ short f2bf16s(float f) {
    __hip_bfloat16 h = __float2bfloat16(f);
    return __builtin_bit_cast(short, h);
}
__device__ __forceinline__ float sigmoidf_(float x) {
    return 1.0f / (1.0f + __expf(-x));
}
__device__ __forceinline__ float tanhf_(float x) {
    x = fminf(fmaxf(x, -15.0f), 15.0f);
    float e = __expf(2.0f * x);
    return (e - 1.0f) / (e + 1.0f);
}

// ================= K1: fp32 -> bf16 convert (x, optionally W_ih) =========
#define XCH (SEQ * BATCH * INP / 8)          // 4,194,304 8-elem chunks
#define WCH (4 * HID * INP / 8)              //   262,144
__global__ __launch_bounds__(256)
void convert_bf16(const float* __restrict__ x, const float* __restrict__ W_ih,
                  unsigned short* __restrict__ xbf, unsigned short* __restrict__ Wbf,
                  int do_w) {
    const size_t total = XCH + (do_w ? WCH : 0);
    for (size_t c = (size_t)blockIdx.x * blockDim.x + threadIdx.x; c < total;
         c += (size_t)gridDim.x * blockDim.x) {
        const float* src; unsigned short* dst;
        if (c < XCH) { src = x + c * 8;            dst = xbf + c * 8; }
        else         { src = W_ih + (c - XCH) * 8; dst = Wbf + (c - XCH) * 8; }
        const float4 a = *(const float4*)src;
        const float4 b = *(const float4*)(src + 4);
        bf16x8 v;
        v[0] = f2bf16s(a.x); v[1] = f2bf16s(a.y);
        v[2] = f2bf16s(a.z); v[3] = f2bf16s(a.w);
        v[4] = f2bf16s(b.x); v[5] = f2bf16s(b.y);
        v[6] = f2bf16s(b.z); v[7] = f2bf16s(b.w);
        *(bf16x8*)dst = v;
    }
}

// ================= K2: xproj = xbf[65536,512] @ Wbf[4096,512]^T (fp32) ====
// grid (512, 32): 128x128 tiles. 4 waves x M=32; acc 2Mx8N 16x16 tiles.
// No LDS: A/B frags straight from global (L1/L2 serve the reuse).
__global__ __launch_bounds__(256)
void xproj_gemm(const unsigned short* __restrict__ xbf,
                const unsigned short* __restrict__ Wbf,
                float* __restrict__ xp) {
    const int tid = threadIdx.x;
    const int w = tid >> 6;
    const int lane = tid & 63;
    const int ln15 = lane & 15;
    const int lgrp = lane >> 4;
    const int k8 = lgrp * 8;
    const int m0 = blockIdx.x * 128 + w * 32 + ln15;   // A row (m0, m0+16)
    const int n0 = blockIdx.y * 128 + ln15;            // B rows n0 + nt*16

    f32x4 acc[2][8];
    #pragma unroll
    for (int i = 0; i < 2; i++)
        #pragma unroll
        for (int j = 0; j < 8; j++) acc[i][j] = (f32x4){0.f, 0.f, 0.f, 0.f};

    #pragma unroll 4
    for (int kt = 0; kt < INP / 32; kt++) {
        const int k = kt * 32 + k8;
        bf16x8 a0 = *(const bf16x8*)(xbf + (size_t)m0 * INP + k);
        bf16x8 a1 = *(const bf16x8*)(xbf + (size_t)(m0 + 16) * INP + k);
        #pragma unroll
        for (int nt = 0; nt < 8; nt++) {
            bf16x8 b = *(const bf16x8*)(Wbf + (size_t)(n0 + nt * 16) * INP + k);
            acc[0][nt] = __builtin_amdgcn_mfma_f32_16x16x32_bf16(a0, b, acc[0][nt], 0, 0, 0);
            acc[1][nt] = __builtin_amdgcn_mfma_f32_16x16x32_bf16(a1, b, acc[1][nt], 0, 0, 0);
        }
    }
    // C/D layout: col = lane&15, row = (lane>>4)*4 + reg
    #pragma unroll
    for (int nt = 0; nt < 8; nt++) {
        const int n = blockIdx.y * 128 + nt * 16 + ln15;
        #pragma unroll
        for (int mi = 0; mi < 2; mi++) {
            const int mb = blockIdx.x * 128 + w * 32 + mi * 16 + lgrp * 4;
            #pragma unroll
            for (int r = 0; r < 4; r++)
                xp[(size_t)(mb + r) * (4 * HID) + n] = acc[mi][nt][r];
        }
    }
}

// ================= K3: recurrent loop (cooperative) =======================
// flag barrier (R5-proven): arrive = one relaxed store to flags[bid];
// wait = wave0 polls 128 flags in parallel, then acquire-inv + syncthreads.
__device__ __forceinline__ void bar_signal(unsigned* flags, int bid, unsigned val) {
    __hip_atomic_store(&flags[bid], val, __ATOMIC_RELAXED,
                       __HIP_MEMORY_SCOPE_AGENT);
}
__device__ __forceinline__ void bar_wait_all(const unsigned* flags, int lane,
                                             unsigned want) {
    const unsigned* p0 = &flags[lane];
    const unsigned* p1 = &flags[64 + lane];
    for (;;) {
        unsigned f0 = __hip_atomic_load(p0, __ATOMIC_RELAXED,
                                        __HIP_MEMORY_SCOPE_AGENT);
        unsigned f1 = __hip_atomic_load(p1, __ATOMIC_RELAXED,
                                        __HIP_MEMORY_SCOPE_AGENT);
        if (__all((f0 >= want) && (f1 >= want))) break;
        __builtin_amdgcn_s_sleep(1);
    }
    __builtin_amdgcn_fence(__ATOMIC_ACQUIRE, "agent");  // inv L1/L2 -> fresh h
}

__global__ __launch_bounds__(NTHR)
void lstm_fused(const float* __restrict__ x,
                const float* __restrict__ W_ih,
                const float* __restrict__ W_hh,
                const float* __restrict__ b_ih,
                const float* __restrict__ b_hh,
                const float* __restrict__ W_fc,
                const float* __restrict__ b_fc,
                float* __restrict__ out,
                unsigned short* __restrict__ h0,
                unsigned short* __restrict__ h1,
                unsigned short* __restrict__ xbf,
                const float* __restrict__ xp,
                int use_xbf, int use_xp,
                unsigned* __restrict__ flags)
{
    // W in MFMA-fragment order [nt][kt][lane][8] -> conflict-free ds_read_b128
    __shared__ short W_sw[2 * NKT * 64 * 8];   // 98304 B
    __shared__ float gw[8][16][33];            // per-wave gate transpose, 16896 B

    const int tid = threadIdx.x;
    const int bid = blockIdx.x;
    const int j0 = bid * BJ;

    // ---------------- one-time init ----------------
    for (int f = tid; f < 2 * NKT * 64; f += NTHR) {    // 12 iters
        const int ln = f & 63;
        const int kt = (f >> 6) % NKT;
        const int nt = f / (NKT * 64);
        const int n = nt * 16 + (ln & 15);              // block n-index 0..31
        const int r = (n >> 3) * HID + j0 + (n & 7);    // global gate row
        const int kbase = kt * 32 + (ln >> 4) * 8;
        short tmp[8];
        #pragma unroll
        for (int j = 0; j < 8; j++) {
            const int k = kbase + j;
            float w = (k < INP) ? W_ih[(size_t)r * INP + k]
                                : W_hh[(size_t)r * HID + (k - INP)];
            tmp[j] = f2bf16s(w);
        }
        *(bf16x8*)&W_sw[(size_t)f * 8] = *(bf16x8*)tmp;
    }
    {   // zero h0: 65536 dwords over 65536 grid threads
        const unsigned g = (unsigned)bid * NTHR + tid;
        ((unsigned*)h0)[g] = 0u;
    }
    if (bid == 0) {
        for (int i = tid; i < NBLK; i += NTHR) flags[i] = 0u;
    }

    const int wave = tid >> 6;          // 0..7 -> M-tile of 16 batch rows
    const int lane = tid & 63;
    const int ln15 = lane & 15;
    const int lgrp = lane >> 4;         // 0..3
    const int arow = wave * 16 + ln15;  // batch row for A fragment
    const int k8 = lgrp * 8;

    // cell-update assignment: 128 cells/wave, 2 per thread
    const int crow = lane >> 2;              // 0..15 (local batch row)
    const int cp   = (lane & 3) * 2;         // col pair base 0,2,4,6
    const int bg   = wave * 16 + crow;       // global batch row
    float c_r[2] = {0.f, 0.f};
    float bias_r[2][4];
    #pragma unroll
    for (int jj = 0; jj < 2; jj++)
        #pragma unroll
        for (int g = 0; g < 4; g++) {
            const int r = g * HID + j0 + cp + jj;
            bias_r[jj][g] = b_ih[r] + b_hh[r];
        }

    // xp column indices for this lane (coop n-order -> global gate row)
    const int nA = ((ln15 >> 3) * HID) + j0 + (ln15 & 7);          // acc00
    const int nB = (((16 + ln15) >> 3) * HID) + j0 + (ln15 & 7);   // acc01

    __syncthreads();
    cg::this_grid().sync();   // publish h0/flags (and ws contents) grid-wide

    const bf16x8* Wl = (const bf16x8*)W_sw + lane;     // + (nt*NKT + kt)*64

    for (int t = 0; t < SEQ; t++) {
        const unsigned short* __restrict__ hp = (t & 1) ? h1 : h0;
        unsigned short* __restrict__ hc       = (t & 1) ? h0 : h1;

        f32x4 acc00, acc01;

        // ---- h-independent part BEFORE the wait (overlaps stragglers) ----
        if (use_xp) {
            // init accumulators from precomputed x-projection
            const float* xrow = xp + ((size_t)t * BATCH + wave * 16 + lgrp * 4) * (4 * HID);
            #pragma unroll
            for (int r = 0; r < 4; r++) {
                acc00[r] = xrow[(size_t)r * (4 * HID) + nA];
                acc01[r] = xrow[(size_t)r * (4 * HID) + nB];
            }
        } else {
            acc00 = (f32x4){0.f,0.f,0.f,0.f};
            acc01 = (f32x4){0.f,0.f,0.f,0.f};
            if (use_xbf) {
                const unsigned short* xr =
                    xbf + (size_t)t * (BATCH * INP) + (size_t)arow * INP + k8;
                #pragma unroll
                for (int kt = 0; kt < NKX; kt++) {
                    bf16x8 a  = *(const bf16x8*)(xr + kt * 32);
                    bf16x8 b0 = Wl[kt * 64];
                    bf16x8 b1 = Wl[(NKT + kt) * 64];
                    acc00 = __builtin_amdgcn_mfma_f32_16x16x32_bf16(a, b0, acc00, 0, 0, 0);
                    acc01 = __builtin_amdgcn_mfma_f32_16x16x32_bf16(a, b1, acc01, 0, 0, 0);
                }
            } else {
                const float* xr =
                    x + (size_t)t * (BATCH * INP) + (size_t)arow * INP + k8;
                #pragma unroll
                for (int kt = 0; kt < NKX; kt++) {
                    const float4 xa = *(const float4*)(xr + kt * 32);
                    const float4 xb = *(const float4*)(xr + kt * 32 + 4);
                    bf16x8 a;
                    a[0]=f2bf16s(xa.x); a[1]=f2bf16s(xa.y); a[2]=f2bf16s(xa.z); a[3]=f2bf16s(xa.w);
                    a[4]=f2bf16s(xb.x); a[5]=f2bf16s(xb.y); a[6]=f2bf16s(xb.z); a[7]=f2bf16s(xb.w);
                    bf16x8 b0 = Wl[kt * 64];
                    bf16x8 b1 = Wl[(NKT + kt) * 64];
                    acc00 = __builtin_amdgcn_mfma_f32_16x16x32_bf16(a, b0, acc00, 0, 0, 0);
                    acc01 = __builtin_amdgcn_mfma_f32_16x16x32_bf16(a, b1, acc01, 0, 0, 0);
                }
            }
        }

        // ---- wait until all blocks published h_t ----
        if (tid < 64) bar_wait_all(flags, lane, (unsigned)t);
        __syncthreads();

        // ---- h-part: normal pipelined b128 loads (L2-deduped, post-inv) ----
        {
            const unsigned short* hr = hp + (size_t)arow * HID + k8;
            #pragma unroll
            for (int kt = 0; kt < NKH; kt++) {
                bf16x8 a  = *(const bf16x8*)(hr + kt * 32);
                bf16x8 b0 = Wl[(NKX + kt) * 64];
                bf16x8 b1 = Wl[(NKT + NKX + kt) * 64];
                acc00 = __builtin_amdgcn_mfma_f32_16x16x32_bf16(a, b0, acc00, 0, 0, 0);
                acc01 = __builtin_amdgcn_mfma_f32_16x16x32_bf16(a, b1, acc01, 0, 0, 0);
            }
        }

        // ---- transpose via wave-private LDS (no block barrier) ----
        {
            const int r0 = lgrp * 4;
            #pragma unroll
            for (int r = 0; r < 4; r++) {
                gw[wave][r0 + r][ln15]      = acc00[r];
                gw[wave][r0 + r][16 + ln15] = acc01[r];
            }
        }

        // ---- cell update: 2 cells/thread (own wave's rows) ----
        {
            unsigned pack = 0;
            #pragma unroll
            for (int jj = 0; jj < 2; jj++) {
                const int dj = cp + jj;
                float ig = gw[wave][crow][dj]      + bias_r[jj][0];
                float fg = gw[wave][crow][8 + dj]  + bias_r[jj][1];
                float gg = gw[wave][crow][16 + dj] + bias_r[jj][2];
                float og = gw[wave][crow][24 + dj] + bias_r[jj][3];
                ig = sigmoidf_(ig); fg = sigmoidf_(fg);
                gg = tanhf_(gg);    og = sigmoidf_(og);
                float c = fg * c_r[jj] + ig * gg;
                c_r[jj] = c;
                float h = og * tanhf_(c);
                pack |= ((unsigned)(unsigned short)f2bf16s(h)) << (16 * jj);
            }
            // write-through to the coherent point
            __hip_atomic_store((unsigned*)(hc + (size_t)bg * HID + j0 + cp),
                               pack, __ATOMIC_RELAXED, __HIP_MEMORY_SCOPE_AGENT);
        }
        asm volatile("s_waitcnt vmcnt(0)" ::: "memory");  // h acked at L3
        __syncthreads();                                   // all waves done

        if (tid == 0) bar_signal(flags, bid, (unsigned)(t + 1));
    }

    // all blocks done; h_last is in h0 (SEQ even). Full fence via cg sync.
    cg::this_grid().sync();

    // ---- FC epilogue: 128000 outputs over 65536 threads (2 iters) ----
    for (unsigned idx = (unsigned)bid * NTHR + tid; idx < BATCH * CLASSES;
         idx += (unsigned)NBLK * NTHR) {
        const int b   = idx / CLASSES;
        const int cls = idx % CLASSES;
        const unsigned short* hrow = h0 + (size_t)b * HID;
        const float* wrow = W_fc + (size_t)cls * HID;
        float acc = 0.f;
        #pragma unroll 4
        for (int k = 0; k < HID; k += 8) {
            bf16x8 hv = *(const bf16x8*)(hrow + k);
            float4 w0 = *(const float4*)(wrow + k);
            float4 w1 = *(const float4*)(wrow + k + 4);
            union { unsigned u; float f; } e;
            float s = 0.f;
            e.u = ((unsigned)(unsigned short)hv[0]) << 16; s += e.f * w0.x;
            e.u = ((unsigned)(unsigned short)hv[1]) << 16; s += e.f * w0.y;
            e.u = ((unsigned)(unsigned short)hv[2]) << 16; s += e.f * w0.z;
            e.u = ((unsigned)(unsigned short)hv[3]) << 16; s += e.f * w0.w;
            e.u = ((unsigned)(unsigned short)hv[4]) << 16; s += e.f * w1.x;
            e.u = ((unsigned)(unsigned short)hv[5]) << 16; s += e.f * w1.y;
            e.u = ((unsigned)(unsigned short)hv[6]) << 16; s += e.f * w1.z;
            e.u = ((unsigned)(unsigned short)hv[7]) << 16; s += e.f * w1.w;
            acc += s;
        }
        out[idx] = acc + b_fc[cls];
    }
}

extern "C" void kernel_launch(void* const* d_in, const int* in_sizes, int n_in,
                              void* d_out, int out_size, void* d_ws, size_t ws_size,
                              hipStream_t stream) {
    const float* x    = (const float*)d_in[0];
    const float* W_ih = (const float*)d_in[1];
    const float* W_hh = (const float*)d_in[2];
    const float* b_ih = (const float*)d_in[3];
    const float* b_hh = (const float*)d_in[4];
    const float* W_fc = (const float*)d_in[5];
    const float* b_fc = (const float*)d_in[6];
    float* out = (float*)d_out;

    // ws layout: h0 | h1 | xbf(64MB) | Wbf(4MB) | xp(1GB)
    const size_t OFF_H1  = (size_t)BATCH * HID * 2;                 // 256 KB
    const size_t OFF_XBF = 2 * OFF_H1;                              // 512 KB
    const size_t XBF_B   = (size_t)SEQ * BATCH * INP * 2;           // 64 MB
    const size_t OFF_WBF = OFF_XBF + XBF_B;
    const size_t WBF_B   = (size_t)4 * HID * INP * 2;               // 4 MB
    const size_t OFF_XP  = OFF_WBF + WBF_B;
    const size_t XP_B    = (size_t)SEQ * BATCH * 4 * HID * 4;       // 1 GB

    unsigned short* h0  = (unsigned short*)d_ws;
    unsigned short* h1  = (unsigned short*)((char*)d_ws + OFF_H1);
    unsigned short* xbf = (unsigned short*)((char*)d_ws + OFF_XBF);
    unsigned short* Wbf = (unsigned short*)((char*)d_ws + OFF_WBF);
    float*          xp  = (float*)((char*)d_ws + OFF_XP);

    int use_xbf = (ws_size >= OFF_XBF + XBF_B) ? 1 : 0;
    int use_xp  = (ws_size >= OFF_XP + XP_B) ? 1 : 0;

    if (use_xbf) {
        convert_bf16<<<dim3(2048), dim3(256), 0, stream>>>(x, W_ih, xbf, Wbf, use_xp);
    }
    if (use_xp) {
        xproj_gemm<<<dim3(512, 32), dim3(256), 0, stream>>>(xbf, Wbf, xp);
    }

    unsigned* flags = (unsigned*)d_out;  // 128 words; overwritten by FC at end

    void* args[] = {&x, &W_ih, &W_hh, &b_ih, &b_hh, &W_fc, &b_fc,
                    &out, &h0, &h1, &xbf, &xp, &use_xbf, &use_xp, &flags};
    hipLaunchCooperativeKernel((void*)lstm_fused, dim3(NBLK), dim3(NTHR),
                               args, 0, stream);
}